// Round 1
// baseline (286.737 us; speedup 1.0000x reference)
//
#include <hip/hip_runtime.h>
#include <hip/hip_fp16.h>
#include <stdint.h>

// Model: v = max_w relu(x @ conv_w^T + conv_b); feat=[v1-v2, v1*v2];
//        out = tanh(feat@fc1^T + b1) @ fc2^T + b2
// B=512, W=128, K=337 (pad 352), OC=300 (pad 320)

#define OC   300
#define OCP  320
#define KD   337
#define KDP  352
#define NBAT 512
#define NWRD 128
#define NKT  11   // 352/32

typedef _Float16 f16x8 __attribute__((ext_vector_type(8)));
typedef float    f32x4 __attribute__((ext_vector_type(4)));

__global__ void prep_w_kernel(const float* __restrict__ cw, __half* __restrict__ W16) {
  int i = blockIdx.x * 256 + threadIdx.x;
  if (i >= OCP * KDP) return;
  int o = i / KDP, d = i - o * KDP;
  float v = (o < OC && d < KD) ? cw[o * KD + d] : 0.f;
  W16[i] = __float2half(v);
}

__global__ void prep_fc1t_kernel(const float* __restrict__ w, float* __restrict__ T) {
  int i = blockIdx.x * 256 + threadIdx.x;
  if (i >= 300 * 600) return;
  int j = i / 600, k = i - j * 600;
  T[k * 300 + j] = w[i];
}

__device__ __forceinline__ uint4 pack8h(const float* f) {
  uint4 u;
  u.x = ((uint32_t)__half_as_ushort(__float2half(f[1])) << 16) | (uint32_t)__half_as_ushort(__float2half(f[0]));
  u.y = ((uint32_t)__half_as_ushort(__float2half(f[3])) << 16) | (uint32_t)__half_as_ushort(__float2half(f[2]));
  u.z = ((uint32_t)__half_as_ushort(__float2half(f[5])) << 16) | (uint32_t)__half_as_ushort(__float2half(f[4]));
  u.w = ((uint32_t)__half_as_ushort(__float2half(f[7])) << 16) | (uint32_t)__half_as_ushort(__float2half(f[6]));
  return u;
}

// 1024 blocks: one per (input sel, batch). 512 thr = 8 waves (2M x 4N).
// A tile 128x32 f16 in LDS (XOR-swizzled 16B slots, double-buffered).
// B fragments read straight from L2-resident padded fp16 weights.
__global__ __launch_bounds__(512) void encode_gemm(
    const float* __restrict__ x1, const float* __restrict__ x2,
    const __half* __restrict__ W16, const float* __restrict__ cb,
    float* __restrict__ V)
{
  __shared__ uint4 At[2][512];        // 2 x 8 KB
  __shared__ float colmax[2][OCP];

  const int tid  = threadIdx.x;
  const int lane = tid & 63;
  const int wid  = tid >> 6;
  const int wm   = wid >> 2;   // 0..1 -> M offset 0/64
  const int wn   = wid & 3;    // 0..3 -> N offset 0/80/160/240
  const int ib   = blockIdx.x;
  const float* xb = (ib < NBAT ? x1 : x2) + (size_t)(ib & (NBAT - 1)) * (NWRD * KD);

  // staging mapping: thread -> (row, 8-elem segment)
  const int srow  = tid >> 2;
  const int sseg  = tid & 3;
  const int sslot = (srow * 4 + sseg) ^ (srow & 7);   // XOR swizzle (bijective)
  const float* sp = xb + srow * KD + sseg * 8;

  f32x4 acc[4][5];
  #pragma unroll
  for (int mi = 0; mi < 4; ++mi)
    #pragma unroll
    for (int ni = 0; ni < 5; ++ni)
      acc[mi][ni] = (f32x4){0.f, 0.f, 0.f, 0.f};

  // prologue: stage kt=0 (dbase max 31 < 337, no guard needed)
  {
    float f[8];
    #pragma unroll
    for (int j = 0; j < 8; ++j) f[j] = sp[j];
    At[0][sslot] = pack8h(f);
  }
  __syncthreads();

  for (int kt = 0; kt < NKT; ++kt) {
    const int cur = kt & 1;

    // issue next tile's global loads EARLY (latency hides under MFMA)
    float f[8];
    if (kt < NKT - 1) {
      const int dbase = (kt + 1) * 32 + sseg * 8;
      const float* p  = sp + (kt + 1) * 32;
      if (dbase + 8 <= KD) {
        #pragma unroll
        for (int j = 0; j < 8; ++j) f[j] = p[j];
      } else {
        #pragma unroll
        for (int j = 0; j < 8; ++j) f[j] = (dbase + j < KD) ? p[j] : 0.f;
      }
    }

    // A fragments from swizzled LDS (2-way bank access = free)
    f16x8 a[4];
    #pragma unroll
    for (int mi = 0; mi < 4; ++mi) {
      int r    = wm * 64 + mi * 16 + (lane & 15);
      int slot = (r * 4 + (lane >> 4)) ^ (r & 7);
      a[mi] = *reinterpret_cast<const f16x8*>(&At[cur][slot]);
    }
    // B fragments direct from global (L2-hot, 16B aligned)
    f16x8 b[5];
    #pragma unroll
    for (int ni = 0; ni < 5; ++ni) {
      int o = wn * 80 + ni * 16 + (lane & 15);
      b[ni] = *reinterpret_cast<const f16x8*>(W16 + (size_t)o * KDP + kt * 32 + (lane >> 4) * 8);
    }

    #pragma unroll
    for (int mi = 0; mi < 4; ++mi)
      #pragma unroll
      for (int ni = 0; ni < 5; ++ni)
        acc[mi][ni] = __builtin_amdgcn_mfma_f32_16x16x32_f16(a[mi], b[ni], acc[mi][ni], 0, 0, 0);

    // convert + write next tile into the other buffer
    if (kt < NKT - 1) {
      At[cur ^ 1][sslot] = pack8h(f);
    }
    __syncthreads();
  }

  // epilogue: max over 128 rows, then relu(max + bias)  (valid since relu monotone, bias per-col)
  // C/D layout: col = lane&15, rows spread over (lane>>4, reg) [m89-verified]
  #pragma unroll
  for (int ni = 0; ni < 5; ++ni) {
    float m = acc[0][ni][0];
    #pragma unroll
    for (int mi = 0; mi < 4; ++mi)
      #pragma unroll
      for (int j = 0; j < 4; ++j)
        m = fmaxf(m, acc[mi][ni][j]);
    m = fmaxf(m, __shfl_xor(m, 16));
    m = fmaxf(m, __shfl_xor(m, 32));
    if (lane < 16) colmax[wm][wn * 80 + ni * 16 + lane] = m;
  }
  __syncthreads();
  if (tid < OCP) {
    float v = fmaxf(colmax[0][tid], colmax[1][tid]);
    if (tid < OC) V[(size_t)ib * OC + tid] = fmaxf(v + cb[tid], 0.f);
  }
}

// 64 blocks x 320 thr, 8 batch items per block.
__global__ __launch_bounds__(320) void head_kernel(
    const float* __restrict__ V, const float* __restrict__ T,
    const float* __restrict__ fc1b, const float* __restrict__ fc2w,
    const float* __restrict__ fc2b, float* __restrict__ out)
{
  __shared__ float feat[8][600];
  __shared__ float partial[8][5];
  const int tid  = threadIdx.x;
  const int lane = tid & 63;
  const int wid  = tid >> 6;
  const int b0   = blockIdx.x * 8;

  for (int idx = tid; idx < 8 * 600; idx += 320) {
    int q = idx / 600, k = idx - q * 600;
    int b = b0 + q;
    int c = (k < 300) ? k : k - 300;
    float a1 = V[(size_t)b * OC + c];
    float a2 = V[(size_t)(NBAT + b) * OC + c];
    feat[q][k] = (k < 300) ? (a1 - a2) : (a1 * a2);
  }
  __syncthreads();

  const int j = tid;
  float h[8] = {0.f, 0.f, 0.f, 0.f, 0.f, 0.f, 0.f, 0.f};
  if (j < 300) {
    for (int k4 = 0; k4 < 150; ++k4) {
      float w0 = T[(k4 * 4 + 0) * 300 + j];
      float w1 = T[(k4 * 4 + 1) * 300 + j];
      float w2 = T[(k4 * 4 + 2) * 300 + j];
      float w3 = T[(k4 * 4 + 3) * 300 + j];
      #pragma unroll
      for (int q = 0; q < 8; ++q) {
        float4 fv = *reinterpret_cast<const float4*>(&feat[q][k4 * 4]);
        h[q] = fmaf(fv.x, w0, h[q]);
        h[q] = fmaf(fv.y, w1, h[q]);
        h[q] = fmaf(fv.z, w2, h[q]);
        h[q] = fmaf(fv.w, w3, h[q]);
      }
    }
  }
  float bias = (j < 300) ? fc1b[j] : 0.f;
  float w2j  = (j < 300) ? fc2w[j] : 0.f;
  #pragma unroll
  for (int q = 0; q < 8; ++q) {
    float g = (j < 300) ? tanhf(h[q] + bias) * w2j : 0.f;
    #pragma unroll
    for (int s = 1; s < 64; s <<= 1) g += __shfl_xor(g, s);
    if (lane == 0) partial[q][wid] = g;
  }
  __syncthreads();
  if (tid < 8) {
    float s = fc2b[0];
    #pragma unroll
    for (int wv = 0; wv < 5; ++wv) s += partial[tid][wv];
    out[b0 + tid] = s;
  }
}

extern "C" void kernel_launch(void* const* d_in, const int* in_sizes, int n_in,
                              void* d_out, int out_size, void* d_ws, size_t ws_size,
                              hipStream_t stream) {
  const float* x1     = (const float*)d_in[0];
  const float* x2     = (const float*)d_in[1];
  const float* conv_w = (const float*)d_in[2];
  const float* conv_b = (const float*)d_in[3];
  const float* fc1_w  = (const float*)d_in[4];
  const float* fc1_b  = (const float*)d_in[5];
  const float* fc2_w  = (const float*)d_in[6];
  const float* fc2_b  = (const float*)d_in[7];
  float* out = (float*)d_out;

  uint8_t* ws = (uint8_t*)d_ws;
  __half* W16 = (__half*)ws;                               // 320*352*2   = 225,280 B
  float*  V   = (float*)(ws + 225280);                     // 1024*300*4  = 1,228,800 B
  float*  T   = (float*)(ws + 225280 + 1228800);           // 600*300*4   = 720,000 B

  prep_w_kernel<<<(OCP * KDP + 255) / 256, 256, 0, stream>>>(conv_w, W16);
  prep_fc1t_kernel<<<(300 * 600 + 255) / 256, 256, 0, stream>>>(fc1_w, T);
  encode_gemm<<<1024, 512, 0, stream>>>(x1, x2, W16, conv_b, V);
  head_kernel<<<64, 320, 0, stream>>>(V, T, fc1_b, fc2_w, fc2_b, out);
}